// Round 1
// baseline (1034.146 us; speedup 1.0000x reference)
//
#include <hip/hip_runtime.h>

// 3-layer weighted GCN, N=100000 nodes, E=1600000 edges, D=H=64, OUT=4.
// Pipeline (per call, all on `stream`):
//   1. deg[i]=1;  deg[dst]+=1 for src!=dst edges;  dis=rsqrt(deg)   (once)
//   2. norm[e] = (src!=dst) ? dis[src]*dis[dst] : 0                 (once)
//   3. per layer L in {0,1}:  y = relu?(in) @ W   (GEMM, W in LDS)
//                             agg[i] = dis[i]^2*y[i] + b            (self-loop+bias init)
//                             agg[dst] += norm[e]*y[src]            (wave-per-edge atomic scatter)
//   4. layer 2: transform FIRST (64->4), then scatter only 4 floats/edge.

#define BLK 256

__global__ void k_init_deg(float* __restrict__ deg, int n) {
    int i = blockIdx.x * blockDim.x + threadIdx.x;
    if (i < n) deg[i] = 1.0f;
}

__global__ void k_count_deg(const int* __restrict__ src, const int* __restrict__ dst,
                            float* __restrict__ deg, int E) {
    int e = blockIdx.x * blockDim.x + threadIdx.x;
    if (e < E) {
        int s = src[e], d = dst[e];
        if (s != d) unsafeAtomicAdd(&deg[d], 1.0f);
    }
}

__global__ void k_rsqrt(float* __restrict__ deg, int n) {
    int i = blockIdx.x * blockDim.x + threadIdx.x;
    if (i < n) deg[i] = rsqrtf(deg[i]);
}

__global__ void k_norm(const int* __restrict__ src, const int* __restrict__ dst,
                       const float* __restrict__ dis, float* __restrict__ nrm, int E) {
    int e = blockIdx.x * blockDim.x + threadIdx.x;
    if (e < E) {
        int s = src[e], d = dst[e];
        nrm[e] = (s != d) ? dis[s] * dis[d] : 0.0f;
    }
}

// out[i][c] = sum_k act(in[i][k]) * W[k][c]   (64x64 W cached in LDS; 4 rows/block)
template <bool RELU>
__global__ void k_gemm64(const float* __restrict__ in, const float* __restrict__ W,
                         float* __restrict__ out, int n) {
    __shared__ float Wl[64 * 64];
    __shared__ float rows[4][64];
    for (int t = threadIdx.x; t < 64 * 64; t += BLK) Wl[t] = W[t];
    int c  = threadIdx.x & 63;
    int r4 = threadIdx.x >> 6;
    for (long base = (long)blockIdx.x * 4; base < n; base += (long)gridDim.x * 4) {
        long row = base + r4;
        __syncthreads();                    // Wl ready (iter0) / rows consumed (iter>0)
        if (row < n) {
            float v = in[row * 64 + c];
            rows[r4][c] = RELU ? fmaxf(v, 0.0f) : v;
        }
        __syncthreads();
        if (row < n) {
            float acc = 0.0f;
#pragma unroll
            for (int k = 0; k < 64; ++k) acc = fmaf(rows[r4][k], Wl[k * 64 + c], acc);
            out[row * 64 + c] = acc;
        }
    }
}

// agg[i][c] = dis[i]^2 * y[i][c] + b[c]
__global__ void k_selfinit(const float* __restrict__ y, const float* __restrict__ dis,
                           const float* __restrict__ b, float* __restrict__ agg, long n64) {
    long i = (long)blockIdx.x * blockDim.x + threadIdx.x;
    if (i < n64) {
        int row = (int)(i >> 6), c = (int)(i & 63);
        float dd = dis[row];
        agg[i] = dd * dd * y[i] + b[c];
    }
}

// wave-per-edge: lane = feature. Coalesced 256B gather + 256B-span atomics.
__global__ void k_scatter(const float* __restrict__ y, const int* __restrict__ src,
                          const int* __restrict__ dst, const float* __restrict__ nrm,
                          float* __restrict__ agg, int E) {
    long gid = (long)blockIdx.x * blockDim.x + threadIdx.x;
    int e    = (int)(gid >> 6);
    int lane = (int)(gid & 63);
    if (e < E) {
        float nm = nrm[e];
        if (nm != 0.0f) {
            long s = src[e], d = dst[e];
            float v = nm * y[s * 64 + lane];
            unsafeAtomicAdd(&agg[d * 64 + lane], v);
        }
    }
}

// ---- layer 2 (64 -> 4): transform first, then 4-wide scatter ----

__global__ void k_gemm4(const float* __restrict__ in, const float* __restrict__ W,
                        float* __restrict__ out, int n) {
    __shared__ float Wl[64 * 4];
    if (threadIdx.x < 64 * 4) Wl[threadIdx.x] = W[threadIdx.x];
    __syncthreads();
    long idx = (long)blockIdx.x * blockDim.x + threadIdx.x;
    long row = idx >> 2;
    int c    = (int)(idx & 3);
    if (row < n) {
        float acc = 0.0f;
#pragma unroll
        for (int k = 0; k < 64; ++k)
            acc = fmaf(fmaxf(in[row * 64 + k], 0.0f), Wl[k * 4 + c], acc);
        out[idx] = acc;
    }
}

__global__ void k_selfinit4(const float* __restrict__ y, const float* __restrict__ dis,
                            const float* __restrict__ b, float* __restrict__ agg, long n4) {
    long i = (long)blockIdx.x * blockDim.x + threadIdx.x;
    if (i < n4) {
        int row = (int)(i >> 2), c = (int)(i & 3);
        float dd = dis[row];
        agg[i] = dd * dd * y[i] + b[c];
    }
}

__global__ void k_scatter4(const float* __restrict__ y, const int* __restrict__ src,
                           const int* __restrict__ dst, const float* __restrict__ nrm,
                           float* __restrict__ agg, int E) {
    long gid = (long)blockIdx.x * blockDim.x + threadIdx.x;
    int e    = (int)(gid >> 2);
    int c    = (int)(gid & 3);
    if (e < E) {
        float nm = nrm[e];
        if (nm != 0.0f) {
            long s = src[e], d = dst[e];
            unsafeAtomicAdd(&agg[d * 4 + c], nm * y[s * 4 + c]);
        }
    }
}

extern "C" void kernel_launch(void* const* d_in, const int* in_sizes, int n_in,
                              void* d_out, int out_size, void* d_ws, size_t ws_size,
                              hipStream_t stream) {
    const float* x  = (const float*)d_in[0];
    const int*   ei = (const int*)d_in[1];
    const float* W0 = (const float*)d_in[2];
    const float* b0 = (const float*)d_in[3];
    const float* W1 = (const float*)d_in[4];
    const float* b1 = (const float*)d_in[5];
    const float* W2 = (const float*)d_in[6];
    const float* b2 = (const float*)d_in[7];
    float* out = (float*)d_out;

    const int n = in_sizes[0] / 64;   // 100000
    const int E = in_sizes[1] / 2;    // 1600000
    const int* src = ei;
    const int* dst = ei + E;

    float* ws   = (float*)d_ws;
    float* dis  = ws;                         // n
    float* nrm  = dis + n;                    // E
    float* bufY = nrm + E;                    // n*64  (transformed features)
    float* bufA = bufY + (size_t)n * 64;      // n*64  (aggregated = next input)
    float* y2   = bufA + (size_t)n * 64;      // n*4

    const long n64 = (long)n * 64, n4 = (long)n * 4;
    const int gN    = (n + BLK - 1) / BLK;
    const int gE    = (E + BLK - 1) / BLK;
    const int gN64  = (int)((n64 + BLK - 1) / BLK);
    const int gN4   = (int)((n4 + BLK - 1) / BLK);
    const int gRows = (n + 3) / 4;
    const int gE64  = (int)(((long)E * 64 + BLK - 1) / BLK);
    const int gE4   = (int)(((long)E * 4 + BLK - 1) / BLK);

    // --- normalization (shared by all layers) ---
    k_init_deg<<<gN, BLK, 0, stream>>>(dis, n);
    k_count_deg<<<gE, BLK, 0, stream>>>(src, dst, dis, E);
    k_rsqrt<<<gN, BLK, 0, stream>>>(dis, n);
    k_norm<<<gE, BLK, 0, stream>>>(src, dst, dis, nrm, E);

    // --- layer 0: y = x@W0 ; agg = dis^2*y + b0 ; scatter ---
    k_gemm64<false><<<gRows, BLK, 0, stream>>>(x, W0, bufY, n);
    k_selfinit<<<gN64, BLK, 0, stream>>>(bufY, dis, b0, bufA, n64);
    k_scatter<<<gE64, BLK, 0, stream>>>(bufY, src, dst, nrm, bufA, E);

    // --- layer 1: y = relu(agg)@W1 ; agg = dis^2*y + b1 ; scatter ---
    k_gemm64<true><<<gRows, BLK, 0, stream>>>(bufA, W1, bufY, n);
    k_selfinit<<<gN64, BLK, 0, stream>>>(bufY, dis, b1, bufA, n64);
    k_scatter<<<gE64, BLK, 0, stream>>>(bufY, src, dst, nrm, bufA, E);

    // --- layer 2 (64->4): transform first, then 4-wide scatter ---
    k_gemm4<<<gN4, BLK, 0, stream>>>(bufA, W2, y2, n);
    k_selfinit4<<<gN4, BLK, 0, stream>>>(y2, dis, b2, out, n4);
    k_scatter4<<<gE4, BLK, 0, stream>>>(y2, src, dst, nrm, out, E);
}

// Round 2
// 516.144 us; speedup vs baseline: 2.0036x; 2.0036x over previous
//
#include <hip/hip_runtime.h>

// 3-layer weighted GCN, N=100000, E=1600000, D=H=64, OUT=4.
// Round 2: replace atomic scatter (400MB write-through per layer, the R1
// bottleneck) with CSR gather. Pipeline:
//   1. cnt[d]++ for src!=dst; dis = rsqrt(cnt+1)
//   2. exclusive scan cnt -> rowstart (3-kernel scan, n=100K, nb=391<=1024)
//   3. fill: srcs[p]=src, nrms[p]=dis[s]*dis[d]  (bucketed by dst)
//   4. layer 0/1: y = relu?(in)@W (LDS GEMM);
//      agg[i][:] = dis[i]^2*y[i][:] + b + sum_e nrm_e * y[src_e][:]
//      (wave-per-node gather, shfl-broadcast edge data, one store per row)
//   5. layer 2: transform first (64->4), then thread-per-(node,c) gather.

#define BLK 256

// ---------- CSR build ----------

__global__ void k_zero_i(int* __restrict__ p, int n) {
    int i = blockIdx.x * blockDim.x + threadIdx.x;
    if (i < n) p[i] = 0;
}

__global__ void k_count(const int* __restrict__ src, const int* __restrict__ dst,
                        int* __restrict__ cnt, int E) {
    int e = blockIdx.x * blockDim.x + threadIdx.x;
    if (e < E) {
        int s = src[e], d = dst[e];
        if (s != d) atomicAdd(&cnt[d], 1);
    }
}

__global__ void k_dis(const int* __restrict__ cnt, float* __restrict__ dis, int n) {
    int i = blockIdx.x * blockDim.x + threadIdx.x;
    if (i < n) dis[i] = rsqrtf((float)cnt[i] + 1.0f);
}

// per-block reduce of cnt -> bsum[block]
__global__ void k_scan1(const int* __restrict__ cnt, int* __restrict__ bsum, int n) {
    __shared__ int sh[BLK];
    int i = blockIdx.x * BLK + threadIdx.x;
    sh[threadIdx.x] = (i < n) ? cnt[i] : 0;
    __syncthreads();
    for (int off = BLK / 2; off > 0; off >>= 1) {
        if (threadIdx.x < off) sh[threadIdx.x] += sh[threadIdx.x + off];
        __syncthreads();
    }
    if (threadIdx.x == 0) bsum[blockIdx.x] = sh[0];
}

// single-block exclusive scan of bsum (nb <= 1024)
__global__ void k_scan2(int* __restrict__ bsum, int nb) {
    __shared__ int sh[1024];
    int v = (threadIdx.x < nb) ? bsum[threadIdx.x] : 0;
    sh[threadIdx.x] = v;
    __syncthreads();
    for (int off = 1; off < 1024; off <<= 1) {
        int t = (threadIdx.x >= off) ? sh[threadIdx.x - off] : 0;
        __syncthreads();
        sh[threadIdx.x] += t;
        __syncthreads();
    }
    if (threadIdx.x < nb) bsum[threadIdx.x] = sh[threadIdx.x] - v;  // exclusive
}

// per-block inclusive scan + block offset -> rowstart (exclusive), cur copy
__global__ void k_scan3(const int* __restrict__ cnt, const int* __restrict__ bsum,
                        int* __restrict__ rowstart, int* __restrict__ cur, int n) {
    __shared__ int sh[BLK];
    int i = blockIdx.x * BLK + threadIdx.x;
    int v = (i < n) ? cnt[i] : 0;
    sh[threadIdx.x] = v;
    __syncthreads();
    for (int off = 1; off < BLK; off <<= 1) {
        int t = (threadIdx.x >= off) ? sh[threadIdx.x - off] : 0;
        __syncthreads();
        sh[threadIdx.x] += t;
        __syncthreads();
    }
    if (i < n) {
        int ex = bsum[blockIdx.x] + sh[threadIdx.x] - v;  // exclusive prefix
        rowstart[i] = ex;
        cur[i] = ex;
        if (i == n - 1) rowstart[n] = bsum[blockIdx.x] + sh[threadIdx.x];
    }
}

__global__ void k_fill(const int* __restrict__ src, const int* __restrict__ dst,
                       const float* __restrict__ dis, int* __restrict__ cur,
                       int* __restrict__ srcs, float* __restrict__ nrms, int E) {
    int e = blockIdx.x * blockDim.x + threadIdx.x;
    if (e < E) {
        int s = src[e], d = dst[e];
        if (s != d) {
            int p = atomicAdd(&cur[d], 1);
            srcs[p] = s;
            nrms[p] = dis[s] * dis[d];
        }
    }
}

// ---------- GEMM (unchanged from R1) ----------

template <bool RELU>
__global__ void k_gemm64(const float* __restrict__ in, const float* __restrict__ W,
                         float* __restrict__ out, int n) {
    __shared__ float Wl[64 * 64];
    __shared__ float rows[4][64];
    for (int t = threadIdx.x; t < 64 * 64; t += BLK) Wl[t] = W[t];
    int c  = threadIdx.x & 63;
    int r4 = threadIdx.x >> 6;
    for (long base = (long)blockIdx.x * 4; base < n; base += (long)gridDim.x * 4) {
        long row = base + r4;
        __syncthreads();
        if (row < n) {
            float v = in[row * 64 + c];
            rows[r4][c] = RELU ? fmaxf(v, 0.0f) : v;
        }
        __syncthreads();
        if (row < n) {
            float acc = 0.0f;
#pragma unroll
            for (int k = 0; k < 64; ++k) acc = fmaf(rows[r4][k], Wl[k * 64 + c], acc);
            out[row * 64 + c] = acc;
        }
    }
}

__global__ void k_gemm4(const float* __restrict__ in, const float* __restrict__ W,
                        float* __restrict__ out, int n) {
    __shared__ float Wl[64 * 4];
    if (threadIdx.x < 64 * 4) Wl[threadIdx.x] = W[threadIdx.x];
    __syncthreads();
    long idx = (long)blockIdx.x * blockDim.x + threadIdx.x;
    long row = idx >> 2;
    int c    = (int)(idx & 3);
    if (row < n) {
        float acc = 0.0f;
#pragma unroll
        for (int k = 0; k < 64; ++k)
            acc = fmaf(fmaxf(in[row * 64 + k], 0.0f), Wl[k * 4 + c], acc);
        out[idx] = acc;
    }
}

// ---------- CSR aggregation (fused self-loop + bias) ----------

// wave-per-node: lane = feature. Edge chunk loaded coalesced, broadcast by shfl.
__global__ void k_aggregate(const float* __restrict__ y, const int* __restrict__ rowstart,
                            const int* __restrict__ srcs, const float* __restrict__ nrms,
                            const float* __restrict__ dis, const float* __restrict__ b,
                            float* __restrict__ agg, int n) {
    int lane = threadIdx.x & 63;
    int node = blockIdx.x * (BLK / 64) + (threadIdx.x >> 6);
    if (node >= n) return;
    int beg = rowstart[node], end = rowstart[node + 1];
    float dd  = dis[node];
    float acc = dd * dd * y[(long)node * 64 + lane] + b[lane];
    for (int base = beg; base < end; base += 64) {
        int rem = end - base;
        if (rem >= 64) {
            int   s  = srcs[base + lane];
            float nm = nrms[base + lane];
#pragma unroll 8
            for (int j = 0; j < 64; ++j)
                acc += __shfl(nm, j) * y[(long)__shfl(s, j) * 64 + lane];
        } else {
            int s = 0; float nm = 0.0f;
            if (lane < rem) { s = srcs[base + lane]; nm = nrms[base + lane]; }
#pragma unroll 4
            for (int j = 0; j < rem; ++j)
                acc += __shfl(nm, j) * y[(long)__shfl(s, j) * 64 + lane];
        }
    }
    agg[(long)node * 64 + lane] = acc;
}

// thread-per-(node,c), c in [0,4)
__global__ void k_agg4(const float* __restrict__ y2, const int* __restrict__ rowstart,
                       const int* __restrict__ srcs, const float* __restrict__ nrms,
                       const float* __restrict__ dis, const float* __restrict__ b,
                       float* __restrict__ out, int n) {
    long t = (long)blockIdx.x * blockDim.x + threadIdx.x;
    int i = (int)(t >> 2), c = (int)(t & 3);
    if (i < n) {
        float dd  = dis[i];
        float acc = dd * dd * y2[(long)i * 4 + c] + b[c];
        int beg = rowstart[i], end = rowstart[i + 1];
        for (int e = beg; e < end; ++e)
            acc += nrms[e] * y2[(long)srcs[e] * 4 + c];
        out[(long)i * 4 + c] = acc;
    }
}

extern "C" void kernel_launch(void* const* d_in, const int* in_sizes, int n_in,
                              void* d_out, int out_size, void* d_ws, size_t ws_size,
                              hipStream_t stream) {
    const float* x  = (const float*)d_in[0];
    const int*   ei = (const int*)d_in[1];
    const float* W0 = (const float*)d_in[2];
    const float* b0 = (const float*)d_in[3];
    const float* W1 = (const float*)d_in[4];
    const float* b1 = (const float*)d_in[5];
    const float* W2 = (const float*)d_in[6];
    const float* b2 = (const float*)d_in[7];
    float* out = (float*)d_out;

    const int n = in_sizes[0] / 64;   // 100000
    const int E = in_sizes[1] / 2;    // 1600000
    const int* src = ei;
    const int* dst = ei + E;

    // workspace layout
    int*   cnt      = (int*)d_ws;                 // n
    int*   rowstart = cnt + n;                    // n+1
    int*   cur      = rowstart + n + 1;           // n
    int*   bsum     = cur + n;                    // 1024
    int*   srcs     = bsum + 1024;                // E
    float* nrms     = (float*)(srcs + E);         // E
    float* dis      = nrms + E;                   // n
    float* bufY     = dis + n;                    // n*64
    float* bufA     = bufY + (size_t)n * 64;      // n*64
    float* y2       = bufY;                       // alias (bufY free in layer 2)

    const int gN    = (n + BLK - 1) / BLK;
    const int gE    = (E + BLK - 1) / BLK;
    const int nb    = gN;                         // scan block count (391)
    const int gWave = (n + (BLK / 64) - 1) / (BLK / 64);   // wave-per-node blocks
    const int gN4   = (int)(((long)n * 4 + BLK - 1) / BLK);
    const int gRows = (n + 3) / 4;

    // --- degree + CSR build (once) ---
    k_zero_i<<<gN, BLK, 0, stream>>>(cnt, n);
    k_count<<<gE, BLK, 0, stream>>>(src, dst, cnt, E);
    k_dis<<<gN, BLK, 0, stream>>>(cnt, dis, n);
    k_scan1<<<nb, BLK, 0, stream>>>(cnt, bsum, n);
    k_scan2<<<1, 1024, 0, stream>>>(bsum, nb);
    k_scan3<<<nb, BLK, 0, stream>>>(cnt, bsum, rowstart, cur, n);
    k_fill<<<gE, BLK, 0, stream>>>(src, dst, dis, cur, srcs, nrms, E);

    // --- layer 0 ---
    k_gemm64<false><<<gRows, BLK, 0, stream>>>(x, W0, bufY, n);
    k_aggregate<<<gWave, BLK, 0, stream>>>(bufY, rowstart, srcs, nrms, dis, b0, bufA, n);

    // --- layer 1 ---
    k_gemm64<true><<<gRows, BLK, 0, stream>>>(bufA, W1, bufY, n);
    k_aggregate<<<gWave, BLK, 0, stream>>>(bufY, rowstart, srcs, nrms, dis, b1, bufA, n);

    // --- layer 2 (64->4): transform first ---
    k_gemm4<<<gN4, BLK, 0, stream>>>(bufA, W2, y2, n);
    k_agg4<<<gN4, BLK, 0, stream>>>(y2, rowstart, srcs, nrms, dis, b2, out, n);
}